// Round 10
// baseline (263.308 us; speedup 1.0000x reference)
//
#include <hip/hip_runtime.h>
#include <hip/hip_bf16.h>
#include <cstdint>

#define TDIM 517
#define FEATD 120
#define NBB 16
#define NHEAD 24
#define NDIM 128
#define NKC 3072            // NHEAD*NDIM
#define MROWS (NBB * TDIM)  // 8272
#define MPAD 8320           // 65 * 128
#define NCOLS (3 * NKC)     // 9216
#define KPAD 128
#define LN_EPS 1e-5f

typedef short bf16x8 __attribute__((ext_vector_type(8)));
typedef short bf16x4 __attribute__((ext_vector_type(4)));
typedef float f32x4 __attribute__((ext_vector_type(4)));

static __device__ __forceinline__ float bf2f(ushort u) {
  union { uint i; float f; } v; v.i = ((uint)u) << 16; return v.f;
}
static __device__ __forceinline__ ushort f2bf(float f) {
  __hip_bfloat16 h = __float2bfloat16(f);   // RNE
  return *reinterpret_cast<ushort*>(&h);
}

// ---------------------------------------------------------------------------
// K0a: x [16][120][517] f32  ->  A [row=(bb*517+tt)][kpad=128] bf16 (f>=120 zero)
// ---------------------------------------------------------------------------
__global__ __launch_bounds__(256) void convert_x_kernel(
    const float* __restrict__ x, ushort* __restrict__ A)
{
  __shared__ float tile[FEATD][65];
  const int tid = threadIdx.x;
  const int bb = blockIdx.y;
  const int t0 = blockIdx.x * 64;
  const int nt = min(64, TDIM - t0);
  for (int idx = tid; idx < FEATD * 64; idx += 256) {
    int f = idx >> 6, tl = idx & 63;
    if (tl < nt) tile[f][tl] = x[((size_t)bb * FEATD + f) * TDIM + t0 + tl];
  }
  __syncthreads();
  for (int c = tid; c < 64 * 16; c += 256) {
    int tl = c >> 4, c8 = c & 15;
    if (tl >= nt) continue;
    ushort u[8];
    if (c8 < 15) {
#pragma unroll
      for (int j = 0; j < 8; ++j) u[j] = f2bf(tile[c8 * 8 + j][tl]);
    } else {
#pragma unroll
      for (int j = 0; j < 8; ++j) u[j] = 0;
    }
    size_t row = (size_t)bb * TDIM + t0 + tl;
    *reinterpret_cast<uint4*>(A + row * KPAD + c8 * 8) = *reinterpret_cast<const uint4*>(u);
  }
}

// ---------------------------------------------------------------------------
// K0b: W{q,k,v} [3072][120] f32 -> B [9216][128] bf16; also zero A tail rows
// ---------------------------------------------------------------------------
__global__ __launch_bounds__(256) void convert_w_kernel(
    const float* __restrict__ Wq, const float* __restrict__ Wk, const float* __restrict__ Wv,
    ushort* __restrict__ B, ushort* __restrict__ A)
{
  const int c = blockIdx.x * 256 + threadIdx.x;
  if (c < NCOLS * 16) {
    int col = c >> 4, c8 = c & 15;
    ushort u[8];
    if (c8 < 15) {
      const float* W = (col < NKC)     ? (Wq + (size_t)col * FEATD)
                     : (col < 2 * NKC) ? (Wk + (size_t)(col - NKC) * FEATD)
                                       : (Wv + (size_t)(col - 2 * NKC) * FEATD);
#pragma unroll
      for (int j = 0; j < 8; ++j) u[j] = f2bf(W[c8 * 8 + j]);
    } else {
#pragma unroll
      for (int j = 0; j < 8; ++j) u[j] = 0;
    }
    *reinterpret_cast<uint4*>(B + (size_t)col * KPAD + c8 * 8) = *reinterpret_cast<const uint4*>(u);
  }
  if (c < (MPAD - MROWS) * 16) {
    uint4 z = {0, 0, 0, 0};
    *reinterpret_cast<uint4*>(A + (size_t)(MROWS + (c >> 4)) * KPAD + (c & 15) * 8) = z;
  }
}

// ---------------------------------------------------------------------------
// K1: MFMA projection GEMM (unchanged from R2)
// ---------------------------------------------------------------------------
__global__ __launch_bounds__(256) void proj_mfma_kernel(
    const ushort* __restrict__ A, const ushort* __restrict__ B,
    const float* __restrict__ bq, const float* __restrict__ bk, const float* __restrict__ bv,
    ushort* __restrict__ qb, ushort* __restrict__ kb, ushort* __restrict__ vb)
{
  __shared__ __align__(16) ushort sA[128 * KPAD];
  __shared__ __align__(16) ushort sB[128 * KPAD];
  __shared__ float sBias[128];
  const int tid  = threadIdx.x;
  const int lane = tid & 63;
  const int wave = tid >> 6;
  const int wm0  = (wave >> 1) * 64;
  const int wn0  = (wave & 1) * 64;
  const int m0   = blockIdx.x * 128;
  const int n0   = blockIdx.y * 128;
  const int mat  = blockIdx.y / 24;
  const int nloc0 = n0 - mat * NKC;
  const float* bias = (mat == 0) ? bq : (mat == 1) ? bk : bv;
  ushort* outb      = (mat == 0) ? qb : (mat == 1) ? kb : vb;

  if (tid < 128) sBias[tid] = bias[nloc0 + tid];

#pragma unroll
  for (int i = 0; i < 8; ++i) {
    int c = tid + i * 256;
    int row = c >> 4, c8 = c & 15;
    uint4 va = *reinterpret_cast<const uint4*>(A + (size_t)(m0 + row) * KPAD + c8 * 8);
    uint4 vb4 = *reinterpret_cast<const uint4*>(B + (size_t)(n0 + row) * KPAD + c8 * 8);
    *reinterpret_cast<uint4*>(&sA[row * KPAD + ((c8 ^ (row & 7)) << 3)]) = va;
    *reinterpret_cast<uint4*>(&sB[row * KPAD + ((c8 ^ (row & 7)) << 3)]) = vb4;
  }
  __syncthreads();

  f32x4 acc[4][4];
#pragma unroll
  for (int i = 0; i < 4; ++i)
#pragma unroll
    for (int j = 0; j < 4; ++j) acc[i][j] = (f32x4){0.f, 0.f, 0.f, 0.f};

  const int rl = lane & 15;
  const int kg = lane >> 4;
#pragma unroll
  for (int s = 0; s < 4; ++s) {
    bf16x8 af[4], bfr[4];
    const int c8 = s * 4 + kg;
#pragma unroll
    for (int i = 0; i < 4; ++i) {
      int row = wm0 + i * 16 + rl;
      af[i] = *reinterpret_cast<const bf16x8*>(&sA[row * KPAD + ((c8 ^ (row & 7)) << 3)]);
      int rowb = wn0 + i * 16 + rl;
      bfr[i] = *reinterpret_cast<const bf16x8*>(&sB[rowb * KPAD + ((c8 ^ (rowb & 7)) << 3)]);
    }
#pragma unroll
    for (int i = 0; i < 4; ++i)
#pragma unroll
      for (int j = 0; j < 4; ++j)
        acc[i][j] = __builtin_amdgcn_mfma_f32_16x16x32_bf16(af[i], bfr[j], acc[i][j], 0, 0, 0);
  }

  __syncthreads();
  ushort* sC = sA;
#pragma unroll
  for (int i = 0; i < 4; ++i)
#pragma unroll
    for (int j = 0; j < 4; ++j) {
      int col = wn0 + j * 16 + rl;
      float bsv = sBias[col];
#pragma unroll
      for (int r = 0; r < 4; ++r) {
        int row = wm0 + i * 16 + kg * 4 + r;
        sC[row * 128 + col] = f2bf(acc[i][j][r] + bsv);
      }
    }
  __syncthreads();
#pragma unroll
  for (int i = 0; i < 8; ++i) {
    int c = tid + i * 256;
    int row = c >> 4, c8 = c & 15;
    int grow = m0 + row;
    if (grow < MROWS)
      *reinterpret_cast<uint4*>(outb + (size_t)grow * NKC + nloc0 + c8 * 8) =
          *reinterpret_cast<const uint4*>(&sC[row * 128 + c8 * 8]);
  }
}

// ---------------------------------------------------------------------------
// K2: MFMA attention + fused LN partial stats. Output now bf16 (R2 evidence:
// bf16 O measured absmax 0.1406 — error budget is proj-input-dominated).
// LN partials stay exact f32 (pre-rounding pv values).
// ---------------------------------------------------------------------------
#define WAVE_LDS 5760
__global__ __launch_bounds__(256) void attn_mfma_kernel(
    const ushort* __restrict__ qb, const ushort* __restrict__ kb,
    const ushort* __restrict__ vb, ushort* __restrict__ obuf,
    float* __restrict__ part)
{
  __shared__ __align__(16) ushort lds[4 * WAVE_LDS];
  const int tid  = threadIdx.x;
  const int wave = tid >> 6;
  const int lane = tid & 63;
  const int c = lane & 15;
  const int g = lane >> 4;
  const int p = blockIdx.x * 4 + wave;
  ushort* vT = lds + wave * WAVE_LDS;   // [n][36]: vT[n*36+m] = V[m][n]
  ushort* wL = vT + 4608;               // [row][36]: wei
  const ushort* qp = qb + (size_t)p * NKC;
  const ushort* kp = kb + (size_t)p * NKC;
  const ushort* vp = vb + (size_t)p * NKC;

  // ---- issue V global loads early (T14: hide under QK^T+softmax) ----
  uint4 vload[6];
#pragma unroll
  for (int it = 0; it < 6; ++it) {
    int idx = it * 64 + lane;
    int m = idx >> 4, n0 = (idx & 15) * 8;
    vload[it] = *reinterpret_cast<const uint4*>(vp + m * 128 + n0);
  }

  // ---- QK^T: S[kk][m], kk rows on A(Q), m cols on B(K) ----
  f32x4 sc[2][2];
#pragma unroll
  for (int i = 0; i < 2; ++i)
#pragma unroll
    for (int j = 0; j < 2; ++j) sc[i][j] = (f32x4){0.f, 0.f, 0.f, 0.f};

#pragma unroll
  for (int s = 0; s < 4; ++s) {
    bf16x8 aq[2], bk2[2];
#pragma unroll
    for (int i = 0; i < 2; ++i)
      aq[i] = *reinterpret_cast<const bf16x8*>(qp + (i * 16 + c) * 128 + s * 32 + g * 8);
#pragma unroll
    for (int j = 0; j < 2; ++j)
      bk2[j] = *reinterpret_cast<const bf16x8*>(kp + (j * 16 + c) * 128 + s * 32 + g * 8);
#pragma unroll
    for (int i = 0; i < 2; ++i)
#pragma unroll
      for (int j = 0; j < 2; ++j)
        sc[i][j] = __builtin_amdgcn_mfma_f32_16x16x32_bf16(aq[i], bk2[j], sc[i][j], 0, 0, 0);
  }

  // ---- softmax over m per row; lane holds S[i*16+g*4+r][j*16+c] ----
#pragma unroll
  for (int i = 0; i < 2; ++i) {
#pragma unroll
    for (int r = 0; r < 4; ++r) {
      float s0 = sc[i][0][r];
      float s1 = (c < 8) ? sc[i][1][r] : -1e30f;
      float mx = fmaxf(s0, s1);
#pragma unroll
      for (int d = 1; d < 16; d <<= 1) mx = fmaxf(mx, __shfl_xor(mx, d));
      float e0 = __expf(s0 - mx);
      float e1 = (c < 8) ? __expf(s1 - mx) : 0.f;
      float sum = e0 + e1;
#pragma unroll
      for (int d = 1; d < 16; d <<= 1) sum += __shfl_xor(sum, d);
      float inv = 1.f / sum;
      int row = i * 16 + g * 4 + r;
      wL[row * 36 + c]      = f2bf(e0 * inv);
      wL[row * 36 + 16 + c] = f2bf(e1 * inv);
    }
  }

  // ---- stage V transposed: vT[n*36 + m] = V[m][n] (scalar scatter) ----
#pragma unroll
  for (int it = 0; it < 6; ++it) {
    int idx = it * 64 + lane;
    int m = idx >> 4, n0 = (idx & 15) * 8;
    uint w0 = vload[it].x, w1 = vload[it].y, w2 = vload[it].z, w3 = vload[it].w;
    vT[(n0 + 0) * 36 + m] = (ushort)(w0 & 0xffff);
    vT[(n0 + 1) * 36 + m] = (ushort)(w0 >> 16);
    vT[(n0 + 2) * 36 + m] = (ushort)(w1 & 0xffff);
    vT[(n0 + 3) * 36 + m] = (ushort)(w1 >> 16);
    vT[(n0 + 4) * 36 + m] = (ushort)(w2 & 0xffff);
    vT[(n0 + 5) * 36 + m] = (ushort)(w2 >> 16);
    vT[(n0 + 6) * 36 + m] = (ushort)(w3 & 0xffff);
    vT[(n0 + 7) * 36 + m] = (ushort)(w3 >> 16);
  }
  // zero pad m=24..31 for all n (ALL halfwords — R3 lesson)
#pragma unroll
  for (int h = 0; h < 16; ++h) {
    int idx = h * 64 + lane;        // 0..1023
    int n = idx >> 3, mm = 24 + (idx & 7);
    vT[n * 36 + mm] = 0;
  }

  // ---- PV A-frags (wei): row=i*16+c, k-chunk g*8 ----
  union FU { bf16x4 h[2]; bf16x8 v; };
  bf16x8 wa[2];
#pragma unroll
  for (int i = 0; i < 2; ++i) {
    FU u;
    u.h[0] = *reinterpret_cast<const bf16x4*>(wL + (i * 16 + c) * 36 + g * 8);
    u.h[1] = *reinterpret_cast<const bf16x4*>(wL + (i * 16 + c) * 36 + g * 8 + 4);
    wa[i] = u.v;
  }

  // ---- PV + O-write (bf16) + LN partial accumulation (f32 exact) ----
  float ls0[4] = {0.f, 0.f, 0.f, 0.f}, ls20[4] = {0.f, 0.f, 0.f, 0.f};
  float ls1[4] = {0.f, 0.f, 0.f, 0.f}, ls21[4] = {0.f, 0.f, 0.f, 0.f};
  ushort* op = obuf + (size_t)p * NKC;
#pragma unroll
  for (int nb = 0; nb < 8; ++nb) {
    FU u;
    const ushort* vrow = vT + (nb * 16 + c) * 36 + g * 8;
    u.h[0] = *reinterpret_cast<const bf16x4*>(vrow);
    u.h[1] = *reinterpret_cast<const bf16x4*>(vrow + 4);
    bf16x8 vf = u.v;
#pragma unroll
    for (int i = 0; i < 2; ++i) {
      f32x4 pv = (f32x4){0.f, 0.f, 0.f, 0.f};
      pv = __builtin_amdgcn_mfma_f32_16x16x32_bf16(wa[i], vf, pv, 0, 0, 0);
      if (i == 0) {
#pragma unroll
        for (int q = 0; q < 4; ++q) {
          op[(g * 4 + q) * 128 + nb * 16 + c] = f2bf(pv[q]);
          ls0[q] += pv[q];
          ls20[q] += pv[q] * pv[q];
        }
      } else if (g < 2) {
#pragma unroll
        for (int q = 0; q < 4; ++q) {
          op[(16 + g * 4 + q) * 128 + nb * 16 + c] = f2bf(pv[q]);
          ls1[q] += pv[q];
          ls21[q] += pv[q] * pv[q];
        }
      }
    }
  }

  // reduce over the 16-lane c-group (xor masks < 16 stay within group)
#pragma unroll
  for (int q = 0; q < 4; ++q) {
#pragma unroll
    for (int d = 1; d < 16; d <<= 1) {
      ls0[q]  += __shfl_xor(ls0[q], d);
      ls20[q] += __shfl_xor(ls20[q], d);
      ls1[q]  += __shfl_xor(ls1[q], d);
      ls21[q] += __shfl_xor(ls21[q], d);
    }
  }
  if (c == 0) {
    float* pr = part + (size_t)p * 48;
#pragma unroll
    for (int q = 0; q < 4; ++q) {
      int kk = g * 4 + q;
      pr[2 * kk]     = ls0[q];
      pr[2 * kk + 1] = ls20[q];
    }
    if (g < 2) {
#pragma unroll
      for (int q = 0; q < 4; ++q) {
        int kk = 16 + g * 4 + q;
        pr[2 * kk]     = ls1[q];
        pr[2 * kk + 1] = ls21[q];
      }
    }
  }
}

// ---------------------------------------------------------------------------
// K3: reduce per-(bb,t) partials -> stats (mu, rstd) per (bb,kk). ~1.6 MB read.
// ---------------------------------------------------------------------------
__global__ __launch_bounds__(256) void ln_part_reduce_kernel(
    const float* __restrict__ part, float* __restrict__ stats)
{
  const int b = blockIdx.x;  // bb*24+kk
  const int bb = b / NHEAD, kk = b % NHEAD;
  const int tid = threadIdx.x;
  float s = 0.f, s2 = 0.f;
  for (int tt = tid; tt < TDIM; tt += 256) {
    const float* pr = part + ((size_t)(bb * TDIM + tt)) * 48 + 2 * kk;
    s += pr[0];
    s2 += pr[1];
  }
  __shared__ float rs[256], rs2[256];
  rs[tid] = s; rs2[tid] = s2;
  __syncthreads();
  for (int off = 128; off > 0; off >>= 1) {
    if (tid < off) { rs[tid] += rs[tid + off]; rs2[tid] += rs2[tid + off]; }
    __syncthreads();
  }
  if (tid == 0) {
    const float inv = 1.f / (NDIM * TDIM);
    float mu = rs[0] * inv;
    float var = rs2[0] * inv - mu * mu;
    stats[b] = mu;
    stats[384 + b] = rsqrtf(var + LN_EPS);
  }
}

// ---------------------------------------------------------------------------
// K4: fused transpose + LN apply, bf16 obuf in, f32 out.
// Block = (bb, kk, n-half of 64, t-chunk of 260). LDS [260t][72] bf16 (37 KB,
// 4 blocks/CU). Reads: 128B segment per t (R9-proven). Writes: thread
// (nl = tid>>2, q = tid&3) streams its row-quarter (65 t) -> ~260B runs,
// 4 threads cover a 1040B+ contiguous row chunk (R9-proven page-friendly).
// Row stride 72 ushorts = 144B (16B-aligned for uint4 LDS writes).
// ---------------------------------------------------------------------------
__global__ __launch_bounds__(256) void transpose_apply_kernel(
    const ushort* __restrict__ obuf, const float* __restrict__ stats,
    const float* __restrict__ gamma, const float* __restrict__ beta,
    float* __restrict__ out)
{
  __shared__ __align__(16) ushort tile[260 * 72];
  const int tid = threadIdx.x;
  const int bb = blockIdx.z, kk = blockIdx.y;
  const int nh = blockIdx.x & 1;        // n half (64 each)
  const int tb = blockIdx.x >> 1;       // t chunk: 0 -> 260, 1 -> 257
  const int t0 = tb * 260;
  const int nt = min(260, TDIM - t0);
  const float mu = stats[bb * NHEAD + kk];
  const float rstd = stats[384 + bb * NHEAD + kk];

  // load [nt][64] bf16 panel (uint4 = 8 bf16)
  for (int idx = tid; idx < 260 * 8; idx += 256) {
    int tl = idx >> 3, n0 = (idx & 7) * 8;
    if (tl < nt) {
      uint4 v = *reinterpret_cast<const uint4*>(
          obuf + ((size_t)(bb * TDIM + t0 + tl)) * NKC + kk * NDIM + nh * 64 + n0);
      *reinterpret_cast<uint4*>(&tile[tl * 72 + n0]) = v;
    }
  }
  __syncthreads();

  // store: row nl, quarter q over t_local [q*65, q*65+qt)
  const int nl = tid >> 2, q = tid & 3;
  const int n = nh * 64 + nl;
  const int base = q * 65;
  const int qt = min(65, nt - base);    // 65,65,65,65 or 65,65,65,62
  float* orow = out + (((size_t)bb * NDIM + n) * NHEAD + kk) * TDIM + t0 + base;
  const float* grow = gamma + (size_t)n * TDIM + t0 + base;
  const float* brow = beta + (size_t)n * TDIM + t0 + base;
  int jj = 0;
  for (; jj + 4 <= qt; jj += 4) {
    float g4[4], b4[4], vals[4];
    __builtin_memcpy(g4, grow + jj, 16);
    __builtin_memcpy(b4, brow + jj, 16);
#pragma unroll
    for (int e = 0; e < 4; ++e)
      vals[e] = (bf2f(tile[(base + jj + e) * 72 + nl]) - mu) * rstd * g4[e] + b4[e];
    __builtin_memcpy(orow + jj, vals, 16);
  }
  for (; jj < qt; ++jj)
    orow[jj] = (bf2f(tile[(base + jj) * 72 + nl]) - mu) * rstd * grow[jj] + brow[jj];
}

// ---------------------------------------------------------------------------
extern "C" void kernel_launch(void* const* d_in, const int* in_sizes, int n_in,
                              void* d_out, int out_size, void* d_ws, size_t ws_size,
                              hipStream_t stream) {
  const float* x     = (const float*)d_in[0];
  const float* Wq    = (const float*)d_in[1];
  const float* bq    = (const float*)d_in[2];
  const float* Wk    = (const float*)d_in[3];
  const float* bk    = (const float*)d_in[4];
  const float* Wv    = (const float*)d_in[5];
  const float* bv    = (const float*)d_in[6];
  const float* gamma = (const float*)d_in[7];
  const float* beta  = (const float*)d_in[8];
  float* out = (float*)d_out;

  char* wsb = (char*)d_ws;
  float* stats = (float*)wsb;                       // 1024 floats
  ushort* A = (ushort*)(wsb + 4096);                // [8320][128] bf16
  ushort* B = A + (size_t)MPAD * KPAD;              // [9216][128] bf16
  ushort* qb = B + (size_t)NCOLS * KPAD;            // [8272][3072] bf16 each
  ushort* kb = qb + (size_t)MROWS * NKC;
  ushort* vb = kb + (size_t)MROWS * NKC;
  ushort* obuf = vb + (size_t)MROWS * NKC;          // [8272][3072] bf16
  float* part = (float*)(obuf + (size_t)MROWS * NKC); // [8272][48] f32

  convert_x_kernel<<<dim3(9, NBB), 256, 0, stream>>>(x, A);
  convert_w_kernel<<<(NCOLS * 16 + 255) / 256, 256, 0, stream>>>(Wq, Wk, Wv, B, A);
  proj_mfma_kernel<<<dim3(MPAD / 128, NCOLS / 128), 256, 0, stream>>>(
      A, B, bq, bk, bv, qb, kb, vb);
  attn_mfma_kernel<<<MROWS / 4, 256, 0, stream>>>(qb, kb, vb, obuf, part);
  ln_part_reduce_kernel<<<NBB * NHEAD, 256, 0, stream>>>(part, stats);
  transpose_apply_kernel<<<dim3(4, NHEAD, NBB), 256, 0, stream>>>(
      obuf, stats, gamma, beta, out);
}

// Round 11
// 158.103 us; speedup vs baseline: 1.6654x; 1.6654x over previous
//
#include <hip/hip_runtime.h>
#include <hip/hip_bf16.h>
#include <cstdint>

#define TDIM 517
#define FEATD 120
#define NBB 16
#define NHEAD 24
#define NDIM 128
#define NKC 3072            // NHEAD*NDIM
#define MROWS (NBB * TDIM)  // 8272
#define MPAD 8320           // 65 * 128
#define NCOLS (3 * NKC)     // 9216
#define KPAD 128
#define LN_EPS 1e-5f

typedef short bf16x8 __attribute__((ext_vector_type(8)));
typedef short bf16x4 __attribute__((ext_vector_type(4)));
typedef float f32x4 __attribute__((ext_vector_type(4)));

static __device__ __forceinline__ float bf2f(ushort u) {
  union { uint i; float f; } v; v.i = ((uint)u) << 16; return v.f;
}
static __device__ __forceinline__ ushort f2bf(float f) {
  __hip_bfloat16 h = __float2bfloat16(f);   // RNE
  return *reinterpret_cast<ushort*>(&h);
}

// ---------------------------------------------------------------------------
// K0a: x [16][120][517] f32  ->  A [row=(bb*517+tt)][kpad=128] bf16 (f>=120 zero)
// ---------------------------------------------------------------------------
__global__ __launch_bounds__(256) void convert_x_kernel(
    const float* __restrict__ x, ushort* __restrict__ A)
{
  __shared__ float tile[FEATD][65];
  const int tid = threadIdx.x;
  const int bb = blockIdx.y;
  const int t0 = blockIdx.x * 64;
  const int nt = min(64, TDIM - t0);
  for (int idx = tid; idx < FEATD * 64; idx += 256) {
    int f = idx >> 6, tl = idx & 63;
    if (tl < nt) tile[f][tl] = x[((size_t)bb * FEATD + f) * TDIM + t0 + tl];
  }
  __syncthreads();
  for (int c = tid; c < 64 * 16; c += 256) {
    int tl = c >> 4, c8 = c & 15;
    if (tl >= nt) continue;
    ushort u[8];
    if (c8 < 15) {
#pragma unroll
      for (int j = 0; j < 8; ++j) u[j] = f2bf(tile[c8 * 8 + j][tl]);
    } else {
#pragma unroll
      for (int j = 0; j < 8; ++j) u[j] = 0;
    }
    size_t row = (size_t)bb * TDIM + t0 + tl;
    *reinterpret_cast<uint4*>(A + row * KPAD + c8 * 8) = *reinterpret_cast<const uint4*>(u);
  }
}

// ---------------------------------------------------------------------------
// K0b: W{q,k,v} [3072][120] f32 -> B [9216][128] bf16; also zero A tail rows
// ---------------------------------------------------------------------------
__global__ __launch_bounds__(256) void convert_w_kernel(
    const float* __restrict__ Wq, const float* __restrict__ Wk, const float* __restrict__ Wv,
    ushort* __restrict__ B, ushort* __restrict__ A)
{
  const int c = blockIdx.x * 256 + threadIdx.x;
  if (c < NCOLS * 16) {
    int col = c >> 4, c8 = c & 15;
    ushort u[8];
    if (c8 < 15) {
      const float* W = (col < NKC)     ? (Wq + (size_t)col * FEATD)
                     : (col < 2 * NKC) ? (Wk + (size_t)(col - NKC) * FEATD)
                                       : (Wv + (size_t)(col - 2 * NKC) * FEATD);
#pragma unroll
      for (int j = 0; j < 8; ++j) u[j] = f2bf(W[c8 * 8 + j]);
    } else {
#pragma unroll
      for (int j = 0; j < 8; ++j) u[j] = 0;
    }
    *reinterpret_cast<uint4*>(B + (size_t)col * KPAD + c8 * 8) = *reinterpret_cast<const uint4*>(u);
  }
  if (c < (MPAD - MROWS) * 16) {
    uint4 z = {0, 0, 0, 0};
    *reinterpret_cast<uint4*>(A + (size_t)(MROWS + (c >> 4)) * KPAD + (c & 15) * 8) = z;
  }
}

// ---------------------------------------------------------------------------
// K1: MFMA projection GEMM (unchanged from R2)
// ---------------------------------------------------------------------------
__global__ __launch_bounds__(256) void proj_mfma_kernel(
    const ushort* __restrict__ A, const ushort* __restrict__ B,
    const float* __restrict__ bq, const float* __restrict__ bk, const float* __restrict__ bv,
    ushort* __restrict__ qb, ushort* __restrict__ kb, ushort* __restrict__ vb)
{
  __shared__ __align__(16) ushort sA[128 * KPAD];
  __shared__ __align__(16) ushort sB[128 * KPAD];
  __shared__ float sBias[128];
  const int tid  = threadIdx.x;
  const int lane = tid & 63;
  const int wave = tid >> 6;
  const int wm0  = (wave >> 1) * 64;
  const int wn0  = (wave & 1) * 64;
  const int m0   = blockIdx.x * 128;
  const int n0   = blockIdx.y * 128;
  const int mat  = blockIdx.y / 24;
  const int nloc0 = n0 - mat * NKC;
  const float* bias = (mat == 0) ? bq : (mat == 1) ? bk : bv;
  ushort* outb      = (mat == 0) ? qb : (mat == 1) ? kb : vb;

  if (tid < 128) sBias[tid] = bias[nloc0 + tid];

#pragma unroll
  for (int i = 0; i < 8; ++i) {
    int c = tid + i * 256;
    int row = c >> 4, c8 = c & 15;
    uint4 va = *reinterpret_cast<const uint4*>(A + (size_t)(m0 + row) * KPAD + c8 * 8);
    uint4 vb4 = *reinterpret_cast<const uint4*>(B + (size_t)(n0 + row) * KPAD + c8 * 8);
    *reinterpret_cast<uint4*>(&sA[row * KPAD + ((c8 ^ (row & 7)) << 3)]) = va;
    *reinterpret_cast<uint4*>(&sB[row * KPAD + ((c8 ^ (row & 7)) << 3)]) = vb4;
  }
  __syncthreads();

  f32x4 acc[4][4];
#pragma unroll
  for (int i = 0; i < 4; ++i)
#pragma unroll
    for (int j = 0; j < 4; ++j) acc[i][j] = (f32x4){0.f, 0.f, 0.f, 0.f};

  const int rl = lane & 15;
  const int kg = lane >> 4;
#pragma unroll
  for (int s = 0; s < 4; ++s) {
    bf16x8 af[4], bfr[4];
    const int c8 = s * 4 + kg;
#pragma unroll
    for (int i = 0; i < 4; ++i) {
      int row = wm0 + i * 16 + rl;
      af[i] = *reinterpret_cast<const bf16x8*>(&sA[row * KPAD + ((c8 ^ (row & 7)) << 3)]);
      int rowb = wn0 + i * 16 + rl;
      bfr[i] = *reinterpret_cast<const bf16x8*>(&sB[rowb * KPAD + ((c8 ^ (rowb & 7)) << 3)]);
    }
#pragma unroll
    for (int i = 0; i < 4; ++i)
#pragma unroll
      for (int j = 0; j < 4; ++j)
        acc[i][j] = __builtin_amdgcn_mfma_f32_16x16x32_bf16(af[i], bfr[j], acc[i][j], 0, 0, 0);
  }

  __syncthreads();
  ushort* sC = sA;
#pragma unroll
  for (int i = 0; i < 4; ++i)
#pragma unroll
    for (int j = 0; j < 4; ++j) {
      int col = wn0 + j * 16 + rl;
      float bsv = sBias[col];
#pragma unroll
      for (int r = 0; r < 4; ++r) {
        int row = wm0 + i * 16 + kg * 4 + r;
        sC[row * 128 + col] = f2bf(acc[i][j][r] + bsv);
      }
    }
  __syncthreads();
#pragma unroll
  for (int i = 0; i < 8; ++i) {
    int c = tid + i * 256;
    int row = c >> 4, c8 = c & 15;
    int grow = m0 + row;
    if (grow < MROWS)
      *reinterpret_cast<uint4*>(outb + (size_t)grow * NKC + nloc0 + c8 * 8) =
          *reinterpret_cast<const uint4*>(&sC[row * 128 + c8 * 8]);
  }
}

// ---------------------------------------------------------------------------
// K2: MFMA attention + fused LN partial stats (bf16 O out, f32 partials)
// ---------------------------------------------------------------------------
#define WAVE_LDS 5760
__global__ __launch_bounds__(256) void attn_mfma_kernel(
    const ushort* __restrict__ qb, const ushort* __restrict__ kb,
    const ushort* __restrict__ vb, ushort* __restrict__ obuf,
    float* __restrict__ part)
{
  __shared__ __align__(16) ushort lds[4 * WAVE_LDS];
  const int tid  = threadIdx.x;
  const int wave = tid >> 6;
  const int lane = tid & 63;
  const int c = lane & 15;
  const int g = lane >> 4;
  const int p = blockIdx.x * 4 + wave;
  ushort* vT = lds + wave * WAVE_LDS;   // [n][36]: vT[n*36+m] = V[m][n]
  ushort* wL = vT + 4608;               // [row][36]: wei
  const ushort* qp = qb + (size_t)p * NKC;
  const ushort* kp = kb + (size_t)p * NKC;
  const ushort* vp = vb + (size_t)p * NKC;

  // ---- issue V global loads early (T14: hide under QK^T+softmax) ----
  uint4 vload[6];
#pragma unroll
  for (int it = 0; it < 6; ++it) {
    int idx = it * 64 + lane;
    int m = idx >> 4, n0 = (idx & 15) * 8;
    vload[it] = *reinterpret_cast<const uint4*>(vp + m * 128 + n0);
  }

  // ---- QK^T: S[kk][m], kk rows on A(Q), m cols on B(K) ----
  f32x4 sc[2][2];
#pragma unroll
  for (int i = 0; i < 2; ++i)
#pragma unroll
    for (int j = 0; j < 2; ++j) sc[i][j] = (f32x4){0.f, 0.f, 0.f, 0.f};

#pragma unroll
  for (int s = 0; s < 4; ++s) {
    bf16x8 aq[2], bk2[2];
#pragma unroll
    for (int i = 0; i < 2; ++i)
      aq[i] = *reinterpret_cast<const bf16x8*>(qp + (i * 16 + c) * 128 + s * 32 + g * 8);
#pragma unroll
    for (int j = 0; j < 2; ++j)
      bk2[j] = *reinterpret_cast<const bf16x8*>(kp + (j * 16 + c) * 128 + s * 32 + g * 8);
#pragma unroll
    for (int i = 0; i < 2; ++i)
#pragma unroll
      for (int j = 0; j < 2; ++j)
        sc[i][j] = __builtin_amdgcn_mfma_f32_16x16x32_bf16(aq[i], bk2[j], sc[i][j], 0, 0, 0);
  }

  // ---- softmax over m per row; lane holds S[i*16+g*4+r][j*16+c] ----
#pragma unroll
  for (int i = 0; i < 2; ++i) {
#pragma unroll
    for (int r = 0; r < 4; ++r) {
      float s0 = sc[i][0][r];
      float s1 = (c < 8) ? sc[i][1][r] : -1e30f;
      float mx = fmaxf(s0, s1);
#pragma unroll
      for (int d = 1; d < 16; d <<= 1) mx = fmaxf(mx, __shfl_xor(mx, d));
      float e0 = __expf(s0 - mx);
      float e1 = (c < 8) ? __expf(s1 - mx) : 0.f;
      float sum = e0 + e1;
#pragma unroll
      for (int d = 1; d < 16; d <<= 1) sum += __shfl_xor(sum, d);
      float inv = 1.f / sum;
      int row = i * 16 + g * 4 + r;
      wL[row * 36 + c]      = f2bf(e0 * inv);
      wL[row * 36 + 16 + c] = f2bf(e1 * inv);
    }
  }

  // ---- stage V transposed: vT[n*36 + m] = V[m][n] (scalar scatter) ----
#pragma unroll
  for (int it = 0; it < 6; ++it) {
    int idx = it * 64 + lane;
    int m = idx >> 4, n0 = (idx & 15) * 8;
    uint w0 = vload[it].x, w1 = vload[it].y, w2 = vload[it].z, w3 = vload[it].w;
    vT[(n0 + 0) * 36 + m] = (ushort)(w0 & 0xffff);
    vT[(n0 + 1) * 36 + m] = (ushort)(w0 >> 16);
    vT[(n0 + 2) * 36 + m] = (ushort)(w1 & 0xffff);
    vT[(n0 + 3) * 36 + m] = (ushort)(w1 >> 16);
    vT[(n0 + 4) * 36 + m] = (ushort)(w2 & 0xffff);
    vT[(n0 + 5) * 36 + m] = (ushort)(w2 >> 16);
    vT[(n0 + 6) * 36 + m] = (ushort)(w3 & 0xffff);
    vT[(n0 + 7) * 36 + m] = (ushort)(w3 >> 16);
  }
  // zero pad m=24..31 for all n (ALL halfwords — R3 lesson)
#pragma unroll
  for (int h = 0; h < 16; ++h) {
    int idx = h * 64 + lane;        // 0..1023
    int n = idx >> 3, mm = 24 + (idx & 7);
    vT[n * 36 + mm] = 0;
  }

  // ---- PV A-frags (wei): row=i*16+c, k-chunk g*8 ----
  union FU { bf16x4 h[2]; bf16x8 v; };
  bf16x8 wa[2];
#pragma unroll
  for (int i = 0; i < 2; ++i) {
    FU u;
    u.h[0] = *reinterpret_cast<const bf16x4*>(wL + (i * 16 + c) * 36 + g * 8);
    u.h[1] = *reinterpret_cast<const bf16x4*>(wL + (i * 16 + c) * 36 + g * 8 + 4);
    wa[i] = u.v;
  }

  // ---- PV + O-write (bf16) + LN partial accumulation (f32 exact) ----
  float ls0[4] = {0.f, 0.f, 0.f, 0.f}, ls20[4] = {0.f, 0.f, 0.f, 0.f};
  float ls1[4] = {0.f, 0.f, 0.f, 0.f}, ls21[4] = {0.f, 0.f, 0.f, 0.f};
  ushort* op = obuf + (size_t)p * NKC;
#pragma unroll
  for (int nb = 0; nb < 8; ++nb) {
    FU u;
    const ushort* vrow = vT + (nb * 16 + c) * 36 + g * 8;
    u.h[0] = *reinterpret_cast<const bf16x4*>(vrow);
    u.h[1] = *reinterpret_cast<const bf16x4*>(vrow + 4);
    bf16x8 vf = u.v;
#pragma unroll
    for (int i = 0; i < 2; ++i) {
      f32x4 pv = (f32x4){0.f, 0.f, 0.f, 0.f};
      pv = __builtin_amdgcn_mfma_f32_16x16x32_bf16(wa[i], vf, pv, 0, 0, 0);
      if (i == 0) {
#pragma unroll
        for (int q = 0; q < 4; ++q) {
          op[(g * 4 + q) * 128 + nb * 16 + c] = f2bf(pv[q]);
          ls0[q] += pv[q];
          ls20[q] += pv[q] * pv[q];
        }
      } else if (g < 2) {
#pragma unroll
        for (int q = 0; q < 4; ++q) {
          op[(16 + g * 4 + q) * 128 + nb * 16 + c] = f2bf(pv[q]);
          ls1[q] += pv[q];
          ls21[q] += pv[q] * pv[q];
        }
      }
    }
  }

  // reduce over the 16-lane c-group (xor masks < 16 stay within group)
#pragma unroll
  for (int q = 0; q < 4; ++q) {
#pragma unroll
    for (int d = 1; d < 16; d <<= 1) {
      ls0[q]  += __shfl_xor(ls0[q], d);
      ls20[q] += __shfl_xor(ls20[q], d);
      ls1[q]  += __shfl_xor(ls1[q], d);
      ls21[q] += __shfl_xor(ls21[q], d);
    }
  }
  if (c == 0) {
    float* pr = part + (size_t)p * 48;
#pragma unroll
    for (int q = 0; q < 4; ++q) {
      int kk = g * 4 + q;
      pr[2 * kk]     = ls0[q];
      pr[2 * kk + 1] = ls20[q];
    }
    if (g < 2) {
#pragma unroll
      for (int q = 0; q < 4; ++q) {
        int kk = 16 + g * 4 + q;
        pr[2 * kk]     = ls1[q];
        pr[2 * kk + 1] = ls21[q];
      }
    }
  }
}

// ---------------------------------------------------------------------------
// K3: reduce per-(bb,t) partials -> stats (mu, rstd) per (bb,kk). ~1.6 MB read.
// ---------------------------------------------------------------------------
__global__ __launch_bounds__(256) void ln_part_reduce_kernel(
    const float* __restrict__ part, float* __restrict__ stats)
{
  const int b = blockIdx.x;  // bb*24+kk
  const int bb = b / NHEAD, kk = b % NHEAD;
  const int tid = threadIdx.x;
  float s = 0.f, s2 = 0.f;
  for (int tt = tid; tt < TDIM; tt += 256) {
    const float* pr = part + ((size_t)(bb * TDIM + tt)) * 48 + 2 * kk;
    s += pr[0];
    s2 += pr[1];
  }
  __shared__ float rs[256], rs2[256];
  rs[tid] = s; rs2[tid] = s2;
  __syncthreads();
  for (int off = 128; off > 0; off >>= 1) {
    if (tid < off) { rs[tid] += rs[tid + off]; rs2[tid] += rs2[tid + off]; }
    __syncthreads();
  }
  if (tid == 0) {
    const float inv = 1.f / (NDIM * TDIM);
    float mu = rs[0] * inv;
    float var = rs2[0] * inv - mu * mu;
    stats[b] = mu;
    stats[384 + b] = rsqrtf(var + LN_EPS);
  }
}

// ---------------------------------------------------------------------------
// K4: fused transpose + LN apply — R9's proven structure, bf16 obuf input.
// Block = (bb, kk, n-group of 32, t-chunk of 256). LDS 256t x 32n f32 (32 KB)
// with per-row rotation col = (n + (t&31) + (t>>5)) & 31 (~2-way both phases).
// Store: lanes vary tpos -> 32 lanes x float4 = 512B contiguous PER
// INSTRUCTION (R10 lesson: coalescing is across lanes within an instruction,
// never across one lane's loop iterations).
// ---------------------------------------------------------------------------
__global__ __launch_bounds__(256) void transpose_apply_kernel(
    const ushort* __restrict__ obuf, const float* __restrict__ stats,
    const float* __restrict__ gamma, const float* __restrict__ beta,
    float* __restrict__ out)
{
  __shared__ float tileF[256 * 32];
  const int tid = threadIdx.x;
  const int bb = blockIdx.z, kk = blockIdx.y;
  const int nq = blockIdx.x / 3, ch = blockIdx.x % 3;
  const int nb = nq * 32;
  const int t0 = ch * 256;
  const float mu = stats[bb * NHEAD + kk];
  const float rstd = stats[384 + bb * NHEAD + kk];

  if (ch < 2) {
    // ---- load [256t][32n] bf16 panel; convert + scatter into rotated LDS ----
#pragma unroll
    for (int i = 0; i < 4; ++i) {
      int idx = tid + i * 256;           // 0..1023
      int tl = idx >> 2, n8 = (idx & 3) * 8;
      uint4 v = *reinterpret_cast<const uint4*>(
          obuf + ((size_t)(bb * TDIM + t0 + tl)) * NKC + kk * NDIM + nb + n8);
      const ushort* u = reinterpret_cast<const ushort*>(&v);
#pragma unroll
      for (int j = 0; j < 8; ++j) {
        int nl = n8 + j;
        int col = (nl + (tl & 31) + (tl >> 5)) & 31;
        tileF[tl * 32 + col] = bf2f(u[j]);
      }
    }
    __syncthreads();

    // ---- LN apply + store: thread (n = p*8 + tid>>5, tpos = tid&31) ----
#pragma unroll
    for (int p = 0; p < 4; ++p) {
      int nl = p * 8 + (tid >> 5);
      int n = nb + nl;
      int tpos = tid & 31;
#pragma unroll
      for (int s = 0; s < 2; ++s) {
        int tg = t0 + s * 128 + tpos * 4;
        const size_t gb = (size_t)n * TDIM + tg;
        float g4[4], b4[4], vals[4];
        __builtin_memcpy(g4, &gamma[gb], 16);
        __builtin_memcpy(b4, &beta[gb], 16);
#pragma unroll
        for (int j = 0; j < 4; ++j) {
          int tl = s * 128 + tpos * 4 + j;
          int col = (nl + (tl & 31) + (tl >> 5)) & 31;
          vals[j] = (tileF[tl * 32 + col] - mu) * rstd * g4[j] + b4[j];
        }
        __builtin_memcpy(out + (((size_t)bb * NDIM + n) * NHEAD + kk) * TDIM + tg,
                         vals, 16);
      }
    }
  } else {
    // ---- tail t = 512..516 (5 t's x 32 n), direct scalar path ----
    for (int c2 = tid; c2 < 32 * 5; c2 += 256) {
      int nl = c2 / 5, tl = c2 % 5;
      int n = nb + nl, tg = 512 + tl;
      float v = bf2f(obuf[((size_t)(bb * TDIM + tg)) * NKC + kk * NDIM + n]);
      out[(((size_t)bb * NDIM + n) * NHEAD + kk) * TDIM + tg] =
          (v - mu) * rstd * gamma[(size_t)n * TDIM + tg] +
          beta[(size_t)n * TDIM + tg];
    }
  }
}

// ---------------------------------------------------------------------------
extern "C" void kernel_launch(void* const* d_in, const int* in_sizes, int n_in,
                              void* d_out, int out_size, void* d_ws, size_t ws_size,
                              hipStream_t stream) {
  const float* x     = (const float*)d_in[0];
  const float* Wq    = (const float*)d_in[1];
  const float* bq    = (const float*)d_in[2];
  const float* Wk    = (const float*)d_in[3];
  const float* bk    = (const float*)d_in[4];
  const float* Wv    = (const float*)d_in[5];
  const float* bv    = (const float*)d_in[6];
  const float* gamma = (const float*)d_in[7];
  const float* beta  = (const float*)d_in[8];
  float* out = (float*)d_out;

  char* wsb = (char*)d_ws;
  float* stats = (float*)wsb;                       // 1024 floats
  ushort* A = (ushort*)(wsb + 4096);                // [8320][128] bf16
  ushort* B = A + (size_t)MPAD * KPAD;              // [9216][128] bf16
  ushort* qb = B + (size_t)NCOLS * KPAD;            // [8272][3072] bf16 each
  ushort* kb = qb + (size_t)MROWS * NKC;
  ushort* vb = kb + (size_t)MROWS * NKC;
  ushort* obuf = vb + (size_t)MROWS * NKC;          // [8272][3072] bf16
  float* part = (float*)(obuf + (size_t)MROWS * NKC); // [8272][48] f32

  convert_x_kernel<<<dim3(9, NBB), 256, 0, stream>>>(x, A);
  convert_w_kernel<<<(NCOLS * 16 + 255) / 256, 256, 0, stream>>>(Wq, Wk, Wv, B, A);
  proj_mfma_kernel<<<dim3(MPAD / 128, NCOLS / 128), 256, 0, stream>>>(
      A, B, bq, bk, bv, qb, kb, vb);
  attn_mfma_kernel<<<MROWS / 4, 256, 0, stream>>>(qb, kb, vb, obuf, part);
  ln_part_reduce_kernel<<<NBB * NHEAD, 256, 0, stream>>>(part, stats);
  transpose_apply_kernel<<<dim3(12, NHEAD, NBB), 256, 0, stream>>>(
      obuf, stats, gamma, beta, out);
}

// Round 12
// 156.085 us; speedup vs baseline: 1.6870x; 1.0129x over previous
//
#include <hip/hip_runtime.h>
#include <hip/hip_bf16.h>
#include <cstdint>

#define TDIM 517
#define FEATD 120
#define NBB 16
#define NHEAD 24
#define NDIM 128
#define NKC 3072            // NHEAD*NDIM
#define MROWS (NBB * TDIM)  // 8272
#define MPAD 8320           // 65 * 128
#define NCOLS (3 * NKC)     // 9216
#define KPAD 128
#define LN_EPS 1e-5f

typedef short bf16x8 __attribute__((ext_vector_type(8)));
typedef short bf16x4 __attribute__((ext_vector_type(4)));
typedef float f32x4 __attribute__((ext_vector_type(4)));

static __device__ __forceinline__ float bf2f(ushort u) {
  union { uint i; float f; } v; v.i = ((uint)u) << 16; return v.f;
}
static __device__ __forceinline__ ushort f2bf(float f) {
  __hip_bfloat16 h = __float2bfloat16(f);   // RNE
  return *reinterpret_cast<ushort*>(&h);
}

// ---------------------------------------------------------------------------
// K0 (merged): blocks 0..143: x [16][120][517] f32 -> A bf16 [row][128];
// blocks 144..719: W{q,k,v} -> B bf16 [9216][128] + zero A tail rows.
// ---------------------------------------------------------------------------
__global__ __launch_bounds__(256) void convert_kernel(
    const float* __restrict__ x,
    const float* __restrict__ Wq, const float* __restrict__ Wk, const float* __restrict__ Wv,
    ushort* __restrict__ A, ushort* __restrict__ B)
{
  __shared__ float tile[FEATD][65];
  const int tid = threadIdx.x;
  const int b = blockIdx.x;

  if (b < 144) {
    const int bb = b / 9;
    const int t0 = (b % 9) * 64;
    const int nt = min(64, TDIM - t0);
    for (int idx = tid; idx < FEATD * 64; idx += 256) {
      int f = idx >> 6, tl = idx & 63;
      if (tl < nt) tile[f][tl] = x[((size_t)bb * FEATD + f) * TDIM + t0 + tl];
    }
    __syncthreads();
    for (int c = tid; c < 64 * 16; c += 256) {
      int tl = c >> 4, c8 = c & 15;
      if (tl >= nt) continue;
      ushort u[8];
      if (c8 < 15) {
#pragma unroll
        for (int j = 0; j < 8; ++j) u[j] = f2bf(tile[c8 * 8 + j][tl]);
      } else {
#pragma unroll
        for (int j = 0; j < 8; ++j) u[j] = 0;
      }
      size_t row = (size_t)bb * TDIM + t0 + tl;
      *reinterpret_cast<uint4*>(A + row * KPAD + c8 * 8) = *reinterpret_cast<const uint4*>(u);
    }
  } else {
    const int c = (b - 144) * 256 + tid;
    if (c < NCOLS * 16) {
      int col = c >> 4, c8 = c & 15;
      ushort u[8];
      if (c8 < 15) {
        const float* W = (col < NKC)     ? (Wq + (size_t)col * FEATD)
                       : (col < 2 * NKC) ? (Wk + (size_t)(col - NKC) * FEATD)
                                         : (Wv + (size_t)(col - 2 * NKC) * FEATD);
#pragma unroll
        for (int j = 0; j < 8; ++j) u[j] = f2bf(W[c8 * 8 + j]);
      } else {
#pragma unroll
        for (int j = 0; j < 8; ++j) u[j] = 0;
      }
      *reinterpret_cast<uint4*>(B + (size_t)col * KPAD + c8 * 8) = *reinterpret_cast<const uint4*>(u);
    }
    if (c < (MPAD - MROWS) * 16) {
      uint4 z = {0, 0, 0, 0};
      *reinterpret_cast<uint4*>(A + (size_t)(MROWS + (c >> 4)) * KPAD + (c & 15) * 8) = z;
    }
  }
}

// ---------------------------------------------------------------------------
// K1: MFMA projection GEMM (unchanged, verified since R2)
// ---------------------------------------------------------------------------
__global__ __launch_bounds__(256) void proj_mfma_kernel(
    const ushort* __restrict__ A, const ushort* __restrict__ B,
    const float* __restrict__ bq, const float* __restrict__ bk, const float* __restrict__ bv,
    ushort* __restrict__ qb, ushort* __restrict__ kb, ushort* __restrict__ vb)
{
  __shared__ __align__(16) ushort sA[128 * KPAD];
  __shared__ __align__(16) ushort sB[128 * KPAD];
  __shared__ float sBias[128];
  const int tid  = threadIdx.x;
  const int lane = tid & 63;
  const int wave = tid >> 6;
  const int wm0  = (wave >> 1) * 64;
  const int wn0  = (wave & 1) * 64;
  const int m0   = blockIdx.x * 128;
  const int n0   = blockIdx.y * 128;
  const int mat  = blockIdx.y / 24;
  const int nloc0 = n0 - mat * NKC;
  const float* bias = (mat == 0) ? bq : (mat == 1) ? bk : bv;
  ushort* outb      = (mat == 0) ? qb : (mat == 1) ? kb : vb;

  if (tid < 128) sBias[tid] = bias[nloc0 + tid];

#pragma unroll
  for (int i = 0; i < 8; ++i) {
    int c = tid + i * 256;
    int row = c >> 4, c8 = c & 15;
    uint4 va = *reinterpret_cast<const uint4*>(A + (size_t)(m0 + row) * KPAD + c8 * 8);
    uint4 vb4 = *reinterpret_cast<const uint4*>(B + (size_t)(n0 + row) * KPAD + c8 * 8);
    *reinterpret_cast<uint4*>(&sA[row * KPAD + ((c8 ^ (row & 7)) << 3)]) = va;
    *reinterpret_cast<uint4*>(&sB[row * KPAD + ((c8 ^ (row & 7)) << 3)]) = vb4;
  }
  __syncthreads();

  f32x4 acc[4][4];
#pragma unroll
  for (int i = 0; i < 4; ++i)
#pragma unroll
    for (int j = 0; j < 4; ++j) acc[i][j] = (f32x4){0.f, 0.f, 0.f, 0.f};

  const int rl = lane & 15;
  const int kg = lane >> 4;
#pragma unroll
  for (int s = 0; s < 4; ++s) {
    bf16x8 af[4], bfr[4];
    const int c8 = s * 4 + kg;
#pragma unroll
    for (int i = 0; i < 4; ++i) {
      int row = wm0 + i * 16 + rl;
      af[i] = *reinterpret_cast<const bf16x8*>(&sA[row * KPAD + ((c8 ^ (row & 7)) << 3)]);
      int rowb = wn0 + i * 16 + rl;
      bfr[i] = *reinterpret_cast<const bf16x8*>(&sB[rowb * KPAD + ((c8 ^ (rowb & 7)) << 3)]);
    }
#pragma unroll
    for (int i = 0; i < 4; ++i)
#pragma unroll
      for (int j = 0; j < 4; ++j)
        acc[i][j] = __builtin_amdgcn_mfma_f32_16x16x32_bf16(af[i], bfr[j], acc[i][j], 0, 0, 0);
  }

  __syncthreads();
  ushort* sC = sA;
#pragma unroll
  for (int i = 0; i < 4; ++i)
#pragma unroll
    for (int j = 0; j < 4; ++j) {
      int col = wn0 + j * 16 + rl;
      float bsv = sBias[col];
#pragma unroll
      for (int r = 0; r < 4; ++r) {
        int row = wm0 + i * 16 + kg * 4 + r;
        sC[row * 128 + col] = f2bf(acc[i][j][r] + bsv);
      }
    }
  __syncthreads();
#pragma unroll
  for (int i = 0; i < 8; ++i) {
    int c = tid + i * 256;
    int row = c >> 4, c8 = c & 15;
    int grow = m0 + row;
    if (grow < MROWS)
      *reinterpret_cast<uint4*>(outb + (size_t)grow * NKC + nloc0 + c8 * 8) =
          *reinterpret_cast<const uint4*>(&sC[row * 128 + c8 * 8]);
  }
}

// ---------------------------------------------------------------------------
// K2: MFMA attention + fused LN partial stats (bf16 O out, f32 partials)
// ---------------------------------------------------------------------------
#define WAVE_LDS 5760
__global__ __launch_bounds__(256) void attn_mfma_kernel(
    const ushort* __restrict__ qb, const ushort* __restrict__ kb,
    const ushort* __restrict__ vb, ushort* __restrict__ obuf,
    float* __restrict__ part)
{
  __shared__ __align__(16) ushort lds[4 * WAVE_LDS];
  const int tid  = threadIdx.x;
  const int wave = tid >> 6;
  const int lane = tid & 63;
  const int c = lane & 15;
  const int g = lane >> 4;
  const int p = blockIdx.x * 4 + wave;
  ushort* vT = lds + wave * WAVE_LDS;   // [n][36]: vT[n*36+m] = V[m][n]
  ushort* wL = vT + 4608;               // [row][36]: wei
  const ushort* qp = qb + (size_t)p * NKC;
  const ushort* kp = kb + (size_t)p * NKC;
  const ushort* vp = vb + (size_t)p * NKC;

  // ---- issue V global loads early (T14: hide under QK^T+softmax) ----
  uint4 vload[6];
#pragma unroll
  for (int it = 0; it < 6; ++it) {
    int idx = it * 64 + lane;
    int m = idx >> 4, n0 = (idx & 15) * 8;
    vload[it] = *reinterpret_cast<const uint4*>(vp + m * 128 + n0);
  }

  // ---- QK^T: S[kk][m], kk rows on A(Q), m cols on B(K) ----
  f32x4 sc[2][2];
#pragma unroll
  for (int i = 0; i < 2; ++i)
#pragma unroll
    for (int j = 0; j < 2; ++j) sc[i][j] = (f32x4){0.f, 0.f, 0.f, 0.f};

#pragma unroll
  for (int s = 0; s < 4; ++s) {
    bf16x8 aq[2], bk2[2];
#pragma unroll
    for (int i = 0; i < 2; ++i)
      aq[i] = *reinterpret_cast<const bf16x8*>(qp + (i * 16 + c) * 128 + s * 32 + g * 8);
#pragma unroll
    for (int j = 0; j < 2; ++j)
      bk2[j] = *reinterpret_cast<const bf16x8*>(kp + (j * 16 + c) * 128 + s * 32 + g * 8);
#pragma unroll
    for (int i = 0; i < 2; ++i)
#pragma unroll
      for (int j = 0; j < 2; ++j)
        sc[i][j] = __builtin_amdgcn_mfma_f32_16x16x32_bf16(aq[i], bk2[j], sc[i][j], 0, 0, 0);
  }

  // ---- softmax over m per row; lane holds S[i*16+g*4+r][j*16+c] ----
#pragma unroll
  for (int i = 0; i < 2; ++i) {
#pragma unroll
    for (int r = 0; r < 4; ++r) {
      float s0 = sc[i][0][r];
      float s1 = (c < 8) ? sc[i][1][r] : -1e30f;
      float mx = fmaxf(s0, s1);
#pragma unroll
      for (int d = 1; d < 16; d <<= 1) mx = fmaxf(mx, __shfl_xor(mx, d));
      float e0 = __expf(s0 - mx);
      float e1 = (c < 8) ? __expf(s1 - mx) : 0.f;
      float sum = e0 + e1;
#pragma unroll
      for (int d = 1; d < 16; d <<= 1) sum += __shfl_xor(sum, d);
      float inv = 1.f / sum;
      int row = i * 16 + g * 4 + r;
      wL[row * 36 + c]      = f2bf(e0 * inv);
      wL[row * 36 + 16 + c] = f2bf(e1 * inv);
    }
  }

  // ---- stage V transposed: vT[n*36 + m] = V[m][n] (scalar scatter) ----
#pragma unroll
  for (int it = 0; it < 6; ++it) {
    int idx = it * 64 + lane;
    int m = idx >> 4, n0 = (idx & 15) * 8;
    uint w0 = vload[it].x, w1 = vload[it].y, w2 = vload[it].z, w3 = vload[it].w;
    vT[(n0 + 0) * 36 + m] = (ushort)(w0 & 0xffff);
    vT[(n0 + 1) * 36 + m] = (ushort)(w0 >> 16);
    vT[(n0 + 2) * 36 + m] = (ushort)(w1 & 0xffff);
    vT[(n0 + 3) * 36 + m] = (ushort)(w1 >> 16);
    vT[(n0 + 4) * 36 + m] = (ushort)(w2 & 0xffff);
    vT[(n0 + 5) * 36 + m] = (ushort)(w2 >> 16);
    vT[(n0 + 6) * 36 + m] = (ushort)(w3 & 0xffff);
    vT[(n0 + 7) * 36 + m] = (ushort)(w3 >> 16);
  }
  // zero pad m=24..31 for all n — FULL coverage (R3 lesson), vectorized:
  // halfwords [n*36+24, n*36+32) = bytes 72n+48..+64, 8B-aligned -> 2 uint2
#pragma unroll
  for (int h = 0; h < 4; ++h) {
    int idx = h * 64 + lane;        // 0..255
    int n = idx >> 1, half = idx & 1;
    uint2 z2 = {0, 0};
    *reinterpret_cast<uint2*>(vT + n * 36 + 24 + half * 4) = z2;
  }

  // ---- PV A-frags (wei): row=i*16+c, k-chunk g*8 ----
  union FU { bf16x4 h[2]; bf16x8 v; };
  bf16x8 wa[2];
#pragma unroll
  for (int i = 0; i < 2; ++i) {
    FU u;
    u.h[0] = *reinterpret_cast<const bf16x4*>(wL + (i * 16 + c) * 36 + g * 8);
    u.h[1] = *reinterpret_cast<const bf16x4*>(wL + (i * 16 + c) * 36 + g * 8 + 4);
    wa[i] = u.v;
  }

  // ---- PV + O-write (bf16) + LN partial accumulation (f32 exact) ----
  float ls0[4] = {0.f, 0.f, 0.f, 0.f}, ls20[4] = {0.f, 0.f, 0.f, 0.f};
  float ls1[4] = {0.f, 0.f, 0.f, 0.f}, ls21[4] = {0.f, 0.f, 0.f, 0.f};
  ushort* op = obuf + (size_t)p * NKC;
#pragma unroll
  for (int nb = 0; nb < 8; ++nb) {
    FU u;
    const ushort* vrow = vT + (nb * 16 + c) * 36 + g * 8;
    u.h[0] = *reinterpret_cast<const bf16x4*>(vrow);
    u.h[1] = *reinterpret_cast<const bf16x4*>(vrow + 4);
    bf16x8 vf = u.v;
#pragma unroll
    for (int i = 0; i < 2; ++i) {
      f32x4 pv = (f32x4){0.f, 0.f, 0.f, 0.f};
      pv = __builtin_amdgcn_mfma_f32_16x16x32_bf16(wa[i], vf, pv, 0, 0, 0);
      if (i == 0) {
#pragma unroll
        for (int q = 0; q < 4; ++q) {
          op[(g * 4 + q) * 128 + nb * 16 + c] = f2bf(pv[q]);
          ls0[q] += pv[q];
          ls20[q] += pv[q] * pv[q];
        }
      } else if (g < 2) {
#pragma unroll
        for (int q = 0; q < 4; ++q) {
          op[(16 + g * 4 + q) * 128 + nb * 16 + c] = f2bf(pv[q]);
          ls1[q] += pv[q];
          ls21[q] += pv[q] * pv[q];
        }
      }
    }
  }

  // reduce over the 16-lane c-group (xor masks < 16 stay within group)
#pragma unroll
  for (int q = 0; q < 4; ++q) {
#pragma unroll
    for (int d = 1; d < 16; d <<= 1) {
      ls0[q]  += __shfl_xor(ls0[q], d);
      ls20[q] += __shfl_xor(ls20[q], d);
      ls1[q]  += __shfl_xor(ls1[q], d);
      ls21[q] += __shfl_xor(ls21[q], d);
    }
  }
  if (c == 0) {
    float* pr = part + (size_t)p * 48;
#pragma unroll
    for (int q = 0; q < 4; ++q) {
      int kk = g * 4 + q;
      pr[2 * kk]     = ls0[q];
      pr[2 * kk + 1] = ls20[q];
    }
    if (g < 2) {
#pragma unroll
      for (int q = 0; q < 4; ++q) {
        int kk = 16 + g * 4 + q;
        pr[2 * kk]     = ls1[q];
        pr[2 * kk + 1] = ls21[q];
      }
    }
  }
}

// ---------------------------------------------------------------------------
// K3: fused stats-reduce + transpose + LN apply.
// Each block redundantly reduces its own (bb,kk)'s 517 partials (4.1 KB,
// L3-hot; identical summation order as the old ln_part_reduce for exact
// determinism), then does the R9-proven transpose: rotated 256x32 f32 LDS,
// stores with lanes varying tpos -> 512B contiguous per instruction.
// Stats-tree barriers double as the tile-load barrier.
// ---------------------------------------------------------------------------
__global__ __launch_bounds__(256) void transpose_apply_kernel(
    const ushort* __restrict__ obuf, const float* __restrict__ part,
    const float* __restrict__ gamma, const float* __restrict__ beta,
    float* __restrict__ out)
{
  __shared__ float tileF[256 * 32];
  __shared__ float rs[256], rs2[256];
  const int tid = threadIdx.x;
  const int bb = blockIdx.z, kk = blockIdx.y;
  const int nq = blockIdx.x / 3, ch = blockIdx.x % 3;
  const int nb = nq * 32;
  const int t0 = ch * 256;

  // ---- phase A: issue tile loads (ch<2 only; no sync needed yet) ----
  if (ch < 2) {
#pragma unroll
    for (int i = 0; i < 4; ++i) {
      int idx = tid + i * 256;           // 0..1023
      int tl = idx >> 2, n8 = (idx & 3) * 8;
      uint4 v = *reinterpret_cast<const uint4*>(
          obuf + ((size_t)(bb * TDIM + t0 + tl)) * NKC + kk * NDIM + nb + n8);
      const ushort* u = reinterpret_cast<const ushort*>(&v);
#pragma unroll
      for (int j = 0; j < 8; ++j) {
        int nl = n8 + j;
        int col = (nl + (tl & 31) + (tl >> 5)) & 31;
        tileF[tl * 32 + col] = bf2f(u[j]);
      }
    }
  }

  // ---- phase B: in-block stats reduction (identical order to old K3) ----
  {
    float s = 0.f, s2 = 0.f;
    for (int tt = tid; tt < TDIM; tt += 256) {
      const float* pr = part + ((size_t)(bb * TDIM + tt)) * 48 + 2 * kk;
      s += pr[0];
      s2 += pr[1];
    }
    rs[tid] = s; rs2[tid] = s2;
  }
  __syncthreads();
  for (int off = 128; off > 0; off >>= 1) {
    if (tid < off) { rs[tid] += rs[tid + off]; rs2[tid] += rs2[tid + off]; }
    __syncthreads();
  }
  const float invN = 1.f / (NDIM * TDIM);
  const float mu = rs[0] * invN;
  const float rstd = rsqrtf(rs2[0] * invN - mu * mu + LN_EPS);

  // ---- phase C: LN apply + store ----
  if (ch < 2) {
#pragma unroll
    for (int p = 0; p < 4; ++p) {
      int nl = p * 8 + (tid >> 5);
      int n = nb + nl;
      int tpos = tid & 31;
#pragma unroll
      for (int s = 0; s < 2; ++s) {
        int tg = t0 + s * 128 + tpos * 4;
        const size_t gb = (size_t)n * TDIM + tg;
        float g4[4], b4[4], vals[4];
        __builtin_memcpy(g4, &gamma[gb], 16);
        __builtin_memcpy(b4, &beta[gb], 16);
#pragma unroll
        for (int j = 0; j < 4; ++j) {
          int tl = s * 128 + tpos * 4 + j;
          int col = (nl + (tl & 31) + (tl >> 5)) & 31;
          vals[j] = (tileF[tl * 32 + col] - mu) * rstd * g4[j] + b4[j];
        }
        __builtin_memcpy(out + (((size_t)bb * NDIM + n) * NHEAD + kk) * TDIM + tg,
                         vals, 16);
      }
    }
  } else {
    // tail t = 512..516 (5 t's x 32 n), direct scalar path
    for (int c2 = tid; c2 < 32 * 5; c2 += 256) {
      int nl = c2 / 5, tl = c2 % 5;
      int n = nb + nl, tg = 512 + tl;
      float v = bf2f(obuf[((size_t)(bb * TDIM + tg)) * NKC + kk * NDIM + n]);
      out[(((size_t)bb * NDIM + n) * NHEAD + kk) * TDIM + tg] =
          (v - mu) * rstd * gamma[(size_t)n * TDIM + tg] +
          beta[(size_t)n * TDIM + tg];
    }
  }
}

// ---------------------------------------------------------------------------
extern "C" void kernel_launch(void* const* d_in, const int* in_sizes, int n_in,
                              void* d_out, int out_size, void* d_ws, size_t ws_size,
                              hipStream_t stream) {
  const float* x     = (const float*)d_in[0];
  const float* Wq    = (const float*)d_in[1];
  const float* bq    = (const float*)d_in[2];
  const float* Wk    = (const float*)d_in[3];
  const float* bk    = (const float*)d_in[4];
  const float* Wv    = (const float*)d_in[5];
  const float* bv    = (const float*)d_in[6];
  const float* gamma = (const float*)d_in[7];
  const float* beta  = (const float*)d_in[8];
  float* out = (float*)d_out;

  char* wsb = (char*)d_ws;
  ushort* A = (ushort*)(wsb + 4096);                // [8320][128] bf16
  ushort* B = A + (size_t)MPAD * KPAD;              // [9216][128] bf16
  ushort* qb = B + (size_t)NCOLS * KPAD;            // [8272][3072] bf16 each
  ushort* kb = qb + (size_t)MROWS * NKC;
  ushort* vb = kb + (size_t)MROWS * NKC;
  ushort* obuf = vb + (size_t)MROWS * NKC;          // [8272][3072] bf16
  float* part = (float*)(obuf + (size_t)MROWS * NKC); // [8272][48] f32

  convert_kernel<<<720, 256, 0, stream>>>(x, Wq, Wk, Wv, A, B);
  proj_mfma_kernel<<<dim3(MPAD / 128, NCOLS / 128), 256, 0, stream>>>(
      A, B, bq, bk, bv, qb, kb, vb);
  attn_mfma_kernel<<<MROWS / 4, 256, 0, stream>>>(qb, kb, vb, obuf, part);
  transpose_apply_kernel<<<dim3(12, NHEAD, NBB), 256, 0, stream>>>(
      obuf, part, gamma, beta, out);
}